// Round 3
// baseline (2171.279 us; speedup 1.0000x reference)
//
#include <hip/hip_runtime.h>

// ---------------------------------------------------------------------------
// HebbianBlock: out(B,T,D) f32; chunked linear-attention style recurrence.
// Pipeline: cast->bf16 | transpose rkTw | vg = (Ww@rk^T)*gw (GEMM) |
//           scan(inter; W-state in MFMA-D layout, x16-MFMA snapshot trick) |
//           intra (S*M2@vg, RMW into inter) | y = out + alpha*io@Wr^T (GEMM)
// ---------------------------------------------------------------------------

typedef __attribute__((ext_vector_type(8))) short short8;
typedef __attribute__((ext_vector_type(4))) short short4v;
typedef __attribute__((ext_vector_type(4))) float f32x4;

#define B_ 4
#define T_ 8192
#define D_ 1024
#define C_ 64
#define NC_ 128

#define DEVI static __device__ __forceinline__

#define EXPF(x) __builtin_expf(x)
#define LOG2F(x) __builtin_log2f(x)
#define EXP2F(x) __builtin_exp2f(x)

DEVI unsigned short f2bf_u(float f) {
  unsigned int u = __float_as_uint(f);
  u += 0x7fffu + ((u >> 16) & 1u);   // round-to-nearest-even
  return (unsigned short)(u >> 16);
}
DEVI short f2bfs(float f) { return (short)f2bf_u(f); }
DEVI float bf2fs(short h) { return __uint_as_float(((unsigned int)(unsigned short)h) << 16); }

DEVI f32x4 mfma16(short8 a, short8 b, f32x4 c) {
  return __builtin_amdgcn_mfma_f32_16x16x32_bf16(a, b, c, 0, 0, 0);
}

// 16x16x16 bf16 MFMA: A/B frags are 4 bf16/lane (k=q*4+j) which matches the
// D-layout rows (q*4+i) — lets the W state feed GEMM1's A operand in-register.
#if defined(__has_builtin)
#if __has_builtin(__builtin_amdgcn_mfma_f32_16x16x16bf16_1k)
#define MFMA16X16(a, b, c) __builtin_amdgcn_mfma_f32_16x16x16bf16_1k(a, b, c, 0, 0, 0)
#elif __has_builtin(__builtin_amdgcn_mfma_f32_16x16x16_bf16)
#define MFMA16X16(a, b, c) __builtin_amdgcn_mfma_f32_16x16x16_bf16(a, b, c, 0, 0, 0)
#endif
#endif

DEVI f32x4 mfma16x16(short4v a, short4v b, f32x4 c) {
#ifdef MFMA16X16
  return MFMA16X16(a, b, c);
#else
  asm volatile("s_nop 1\n\t"
               "v_mfma_f32_16x16x16_bf16 %0, %1, %2, %0\n\t"
               "s_nop 7\n\t"
               "s_nop 7"
               : "+v"(c) : "v"(a), "v"(b));
  return c;
#endif
}

// ---------------------------------------------------------------- cast f32->bf16
__global__ __launch_bounds__(256) void k_cast(const float* __restrict__ src,
                                              short* __restrict__ dst, int n8) {
  int i = blockIdx.x * 256 + threadIdx.x;
  if (i >= n8) return;
  const float4* s = (const float4*)src;
  float4 a = s[2 * i], b = s[2 * i + 1];
  short8 o;
  o[0] = f2bfs(a.x); o[1] = f2bfs(a.y); o[2] = f2bfs(a.z); o[3] = f2bfs(a.w);
  o[4] = f2bfs(b.x); o[5] = f2bfs(b.y); o[6] = f2bfs(b.z); o[7] = f2bfs(b.w);
  *((short8*)dst + i) = o;
}

// ---------------------------------------------------------------- rkTw transpose
// rkTw[b][e][t] = rk[b][t-1][e]  (the shifted w sequence, e-major, t contiguous)
__global__ __launch_bounds__(256) void k_transpose(const short* __restrict__ rk,
                                                   short* __restrict__ rkTw) {
  __shared__ short tile[64][72];   // [t_local][e_local], +8 pad
  const int tid = threadIdx.x;
  const int t0 = blockIdx.x * 64;  // OUTPUT t range [t0, t0+64)
  const int e0 = blockIdx.y * 64;
  const int b = blockIdx.z;
  const short* src = rk + (size_t)b * T_ * D_;
  const int tl = tid >> 3, seg = tid & 7;
#pragma unroll
  for (int p = 0; p < 2; ++p) {
    int t = t0 - 1 + p * 32 + tl;   // input row (shift by -1)
    short8 v;
    if (t >= 0) v = *(const short8*)(src + (size_t)t * D_ + e0 + seg * 8);
    else v = (short8){0, 0, 0, 0, 0, 0, 0, 0};
    *(short8*)&tile[p * 32 + tl][seg * 8] = v;
  }
  __syncthreads();
  const int el = tid >> 2, ts = (tid & 3) * 16;
  short8 o0, o1;
#pragma unroll
  for (int j = 0; j < 8; ++j) { o0[j] = tile[ts + j][el]; o1[j] = tile[ts + 8 + j][el]; }
  short* dst = rkTw + ((size_t)b * D_ + e0 + el) * T_ + t0 + ts;
  *(short8*)(dst) = o0;
  *(short8*)(dst + 8) = o1;
}

// ---------------------------------------------------------------- vg = (Ww @ rk^T) * gw
// M = D (Ww rows d), N = B*T, K = D.  Output vg[b][d][t] = v[t][d]*gamma^(63-(t&63)).
__global__ __launch_bounds__(256) void k_gemm_v(const short* __restrict__ Aw,
                                                const short* __restrict__ Bx,
                                                short* __restrict__ vg,
                                                const float* __restrict__ decay_p) {
  __shared__ short As[128][72];
  __shared__ short Bs[128][72];
  const int tid = threadIdx.x;
  const int lane = tid & 63, wv = tid >> 6;
  const int wm = (wv >> 1) * 64, wn = (wv & 1) * 64;
  const int l16 = lane & 15, q = lane >> 4;
  const int m0 = blockIdx.y * 128;
  const int n0 = blockIdx.x * 128;
  const float gamma = 1.f / (1.f + EXPF(-decay_p[0]));
  const float lg2g = LOG2F(gamma);
  f32x4 acc[4][4];
  for (int a = 0; a < 4; ++a)
    for (int b = 0; b < 4; ++b) acc[a][b] = (f32x4){0.f, 0.f, 0.f, 0.f};
  const int lrow = tid >> 3, lseg = tid & 7;
  const short* Ap = Aw + (size_t)(m0 + lrow) * D_ + lseg * 8;
  const short* Bp = Bx + (size_t)(n0 + lrow) * D_ + lseg * 8;
  for (int kb = 0; kb < D_; kb += 64) {
#pragma unroll
    for (int p = 0; p < 4; ++p) {
      *(short8*)&As[lrow + p * 32][lseg * 8] = *(const short8*)(Ap + (size_t)(p * 32) * D_ + kb);
      *(short8*)&Bs[lrow + p * 32][lseg * 8] = *(const short8*)(Bp + (size_t)(p * 32) * D_ + kb);
    }
    __syncthreads();
#pragma unroll
    for (int ks = 0; ks < 2; ++ks) {
      short8 af[4], bfr[4];
#pragma unroll
      for (int mt = 0; mt < 4; ++mt) af[mt] = *(const short8*)&As[wm + mt * 16 + l16][ks * 32 + q * 8];
#pragma unroll
      for (int nt = 0; nt < 4; ++nt) bfr[nt] = *(const short8*)&Bs[wn + nt * 16 + l16][ks * 32 + q * 8];
#pragma unroll
      for (int mt = 0; mt < 4; ++mt)
#pragma unroll
        for (int nt = 0; nt < 4; ++nt) acc[mt][nt] = mfma16(af[mt], bfr[nt], acc[mt][nt]);
    }
    __syncthreads();
  }
  const int b = n0 >> 13;                // T_ = 8192 rows per batch
  const int tbase = (n0 & (T_ - 1)) + wn;
  short* outp = vg + (size_t)b * D_ * T_;
#pragma unroll
  for (int nt = 0; nt < 4; ++nt) {
    const float gsc = EXP2F(lg2g * (float)(63 - ((tbase + nt * 16 + l16) & 63)));
#pragma unroll
    for (int mt = 0; mt < 4; ++mt)
#pragma unroll
      for (int i = 0; i < 4; ++i) {
        int d = m0 + wm + mt * 16 + q * 4 + i;
        int t = tbase + nt * 16 + l16;
        outp[(size_t)d * T_ + t] = f2bfs(acc[mt][nt][i] * gsc);
      }
  }
}

// ---------------------------------------------------------------- scan
// grid (64 d-tiles, 4 b). Block owns W[d0:d0+16][0:1024]; wave wv owns e-slice
// [wv*256, wv*256+256) as 16 subtiles in MFMA-D layout:
//   Wacc[es][i] = W[d0 + (lane&15)][wv*256 + es*16 + (lane>>4)*4 + i]
// GEMM2 (update): D[m=e][n=d] += A(w^T from rkTw) x32 . B(vg) x32
// GEMM1 (inter):  D[m=d][n=c] += A(bf16 snapshot of Wacc, x16) . B(rk, x16)
// inter partials (e-sliced) reduced across waves via LDS fp32.
__global__ __launch_bounds__(256) void k_scan(const short* __restrict__ rk,
                                              const short* __restrict__ rkTw,
                                              const short* __restrict__ vg,
                                              short* __restrict__ inter_,
                                              const float* __restrict__ decay_p) {
  __shared__ float red[2][4][64][20];   // [parity][wave][c][d] fp32 partials
  const int tid = threadIdx.x;
  const int lane = tid & 63, wv = tid >> 6;
  const int l16 = lane & 15, q = lane >> 4;
  const int d0 = blockIdx.x * 16, b = blockIdx.y;
  const float gamma = 1.f / (1.f + EXPF(-decay_p[0]));
  const float lg2g = LOG2F(gamma);
  const float gC = EXP2F(64.f * lg2g);
  const int rc = tid >> 2;              // reduce: c index 0..63
  const int rdg = (tid & 3) * 4;        // reduce: d group
  const float csc = EXP2F(lg2g * (float)rc);   // dec_inter[c]

  const short* rk_b = rk + (size_t)b * T_ * D_;
  const short* rkT_b = rkTw + (size_t)b * D_ * T_;
  const short* vg_b = vg + (size_t)b * D_ * T_;
  short* int_b = inter_ + (size_t)b * T_ * D_;

  // thread-constant address parts
  const short* g1base = rk_b + (size_t)l16 * D_ + wv * 256 + q * 4;   // + t0*D + ct*16*D + es*16
  const short* g2base = rkT_b + (size_t)(wv * 256 + l16) * T_ + q * 8; // + es*16*T + t0 (+32)
  const short* gvbase = vg_b + (size_t)(d0 + l16) * T_ + q * 8;        // + t0 (+32)

  f32x4 Wacc[16];
#pragma unroll
  for (int j = 0; j < 16; ++j) Wacc[j] = (f32x4){0.f, 0.f, 0.f, 0.f};

  for (int ch = 0; ch < NC_; ++ch) {
    const int t0 = ch << 6;
    // 1. snapshot chunk-start W as x16 A-frags (pure VALU), then decay state
    short4v afW[16];
#pragma unroll
    for (int es = 0; es < 16; ++es) {
      afW[es][0] = f2bfs(Wacc[es][0]);
      afW[es][1] = f2bfs(Wacc[es][1]);
      afW[es][2] = f2bfs(Wacc[es][2]);
      afW[es][3] = f2bfs(Wacc[es][3]);
      Wacc[es][0] *= gC; Wacc[es][1] *= gC; Wacc[es][2] *= gC; Wacc[es][3] *= gC;
    }
    // 2. GEMM2 B-frags (vg), shared across all e-subtiles
    short8 bv0 = *(const short8*)(gvbase + t0);
    short8 bv1 = *(const short8*)(gvbase + t0 + 32);
    // 3. GEMM1: inter partial over this wave's 256-e slice (x16 MFMA)
    f32x4 iacc[4];
#pragma unroll
    for (int ct = 0; ct < 4; ++ct) iacc[ct] = (f32x4){0.f, 0.f, 0.f, 0.f};
    const short* g1t = g1base + (size_t)t0 * D_;
#pragma unroll
    for (int es = 0; es < 16; ++es) {
#pragma unroll
      for (int ct = 0; ct < 4; ++ct) {
        short4v bfr = *(const short4v*)(g1t + (size_t)(ct * 16) * D_ + es * 16);
        iacc[ct] = mfma16x16(afW[es], bfr, iacc[ct]);
      }
    }
    // 4. GEMM2: W += w^T @ vg (x32 MFMA), A from rkTw (pre-shifted)
#pragma unroll
    for (int es = 0; es < 16; ++es) {
      const short* aa = g2base + (size_t)(es * 16) * T_ + t0;
      short8 a0 = *(const short8*)(aa);
      short8 a1 = *(const short8*)(aa + 32);
      Wacc[es] = mfma16(a0, bv0, Wacc[es]);
      Wacc[es] = mfma16(a1, bv1, Wacc[es]);
    }
    // 5. cross-wave reduce of inter partials, scale by gamma^c, store bf16
    const int p = ch & 1;
#pragma unroll
    for (int ct = 0; ct < 4; ++ct)
      *(f32x4*)&red[p][wv][ct * 16 + l16][q * 4] = iacc[ct];
    __syncthreads();
    f32x4 s0 = *(const f32x4*)&red[p][0][rc][rdg];
    f32x4 s1 = *(const f32x4*)&red[p][1][rc][rdg];
    f32x4 s2 = *(const f32x4*)&red[p][2][rc][rdg];
    f32x4 s3 = *(const f32x4*)&red[p][3][rc][rdg];
    short4v o;
#pragma unroll
    for (int j = 0; j < 4; ++j) o[j] = f2bfs((s0[j] + s1[j] + s2[j] + s3[j]) * csc);
    *(short4v*)(int_b + (size_t)(t0 + rc) * D_ + d0 + rdg) = o;
  }
}

// ---------------------------------------------------------------- intra chunk
// grid (128 chunks, 4 b): S = r@w^T (K=1024), P2 = S*[c>cp]*gamma^(c-64),
// intra = P2@vg  (vg carries gamma^(63-cp); product = gamma^(c-1-cp) exact).
// RMW-adds into the inter buffer.
__global__ __launch_bounds__(256) void k_intra(const short* __restrict__ rk,
                                               const short* __restrict__ vg,
                                               short* __restrict__ io,
                                               const float* __restrict__ decay_p) {
  __shared__ short rs[65][264];
  __shared__ short P[64][72];
  __shared__ short vs[256][72];
  const int tid = threadIdx.x;
  const int lane = tid & 63, wv = tid >> 6;
  const int l16 = lane & 15, q = lane >> 4;
  const int ch = blockIdx.x, b = blockIdx.y;
  const int t0 = ch << 6;
  const float gamma = 1.f / (1.f + EXPF(-decay_p[0]));
  const float lg2g = LOG2F(gamma);
  const short* rk_b = rk + (size_t)b * T_ * D_;
  f32x4 Sacc[4];
#pragma unroll
  for (int j = 0; j < 4; ++j) Sacc[j] = (f32x4){0.f, 0.f, 0.f, 0.f};

  for (int s = 0; s < 4; ++s) {
    const int e0 = s << 8;
#pragma unroll
    for (int p = 0; p < 9; ++p) {
      int idx = p * 256 + tid;
      if (idx < 2080) {
        int row = idx >> 5, seg = idx & 31;
        int t = t0 - 1 + row;
        short8 v8;
        if (t >= 0) v8 = *(const short8*)(rk_b + (size_t)t * D_ + e0 + seg * 8);
        else v8 = (short8){0, 0, 0, 0, 0, 0, 0, 0};
        *(short8*)&rs[row][seg * 8] = v8;
      }
    }
    __syncthreads();
#pragma unroll
    for (int ks = 0; ks < 8; ++ks) {
      short8 af = *(const short8*)&rs[wv * 16 + l16 + 1][ks * 32 + q * 8];   // r rows
#pragma unroll
      for (int nt = 0; nt < 4; ++nt) {
        short8 bfr = *(const short8*)&rs[nt * 16 + l16][ks * 32 + q * 8];    // w rows
        Sacc[nt] = mfma16(af, bfr, Sacc[nt]);
      }
    }
    __syncthreads();
  }
  // mask: P2[c][cp] = S * gamma^(c-64) for c>cp, else 0
#pragma unroll
  for (int nt = 0; nt < 4; ++nt)
#pragma unroll
    for (int i = 0; i < 4; ++i) {
      int c = wv * 16 + q * 4 + i;
      int cp = nt * 16 + l16;
      float m = (c > cp) ? EXP2F(lg2g * (float)(c - 64)) : 0.f;
      P[c][cp] = f2bfs(Sacc[nt][i] * m);
    }
  __syncthreads();
  const short* vsrc = vg + (size_t)b * D_ * T_ + (size_t)tid * T_ + t0;
  size_t base = (size_t)b * T_ * D_;
  for (int p = 0; p < 4; ++p) {
    const short* sp = vsrc + (size_t)(p * 256) * T_;
#pragma unroll
    for (int seg = 0; seg < 8; ++seg)
      *(short8*)&vs[tid][seg * 8] = *(const short8*)(sp + seg * 8);
    __syncthreads();
    f32x4 acc[4][4];
#pragma unroll
    for (int a = 0; a < 4; ++a)
#pragma unroll
      for (int bb = 0; bb < 4; ++bb) acc[a][bb] = (f32x4){0.f, 0.f, 0.f, 0.f};
#pragma unroll
    for (int ks2 = 0; ks2 < 2; ++ks2) {
      short8 af[4];
#pragma unroll
      for (int mt = 0; mt < 4; ++mt) af[mt] = *(const short8*)&P[mt * 16 + l16][ks2 * 32 + q * 8];
#pragma unroll
      for (int nt = 0; nt < 4; ++nt) {
        short8 bfr = *(const short8*)&vs[wv * 64 + nt * 16 + l16][ks2 * 32 + q * 8];
#pragma unroll
        for (int mt = 0; mt < 4; ++mt) acc[mt][nt] = mfma16(af[mt], bfr, acc[mt][nt]);
      }
    }
#pragma unroll
    for (int mt = 0; mt < 4; ++mt)
#pragma unroll
      for (int nt = 0; nt < 4; ++nt)
#pragma unroll
        for (int i = 0; i < 4; ++i) {
          int c = mt * 16 + q * 4 + i;
          int d = p * 256 + wv * 64 + nt * 16 + l16;
          size_t idx = base + (size_t)(t0 + c) * D_ + d;
          io[idx] = f2bfs(bf2fs(io[idx]) + acc[mt][nt][i]);   // RMW add onto inter
        }
    __syncthreads();
  }
}

// ---------------------------------------------------------------- final GEMM
// y = out + alpha * io @ Wr^T.  M = B*T, N = D, K = D.
__global__ __launch_bounds__(256) void k_gemm_final(const short* __restrict__ io,
                                                    const short* __restrict__ Wr,
                                                    const float* __restrict__ xin,
                                                    float* __restrict__ y,
                                                    const float* __restrict__ la_p) {
  __shared__ short As[128][72];
  __shared__ short Bs[128][72];
  const float alpha = EXPF(la_p[0]);
  const int tid = threadIdx.x;
  const int lane = tid & 63, wv = tid >> 6;
  const int wm = (wv >> 1) * 64, wn = (wv & 1) * 64;
  const int l16 = lane & 15, q = lane >> 4;
  const int m0 = blockIdx.x * 128;
  const int n0 = blockIdx.y * 128;
  f32x4 acc[4][4];
  for (int a = 0; a < 4; ++a)
    for (int b = 0; b < 4; ++b) acc[a][b] = (f32x4){0.f, 0.f, 0.f, 0.f};
  const int lrow = tid >> 3, lseg = tid & 7;
  for (int kb = 0; kb < D_; kb += 64) {
#pragma unroll
    for (int p = 0; p < 4; ++p) {
      size_t aoff = (size_t)(m0 + lrow + p * 32) * D_ + kb + lseg * 8;
      *(short8*)&As[lrow + p * 32][lseg * 8] = *(const short8*)(io + aoff);
      *(short8*)&Bs[lrow + p * 32][lseg * 8] =
          *(const short8*)(Wr + (size_t)(n0 + lrow + p * 32) * D_ + kb + lseg * 8);
    }
    __syncthreads();
#pragma unroll
    for (int ks = 0; ks < 2; ++ks) {
      short8 af[4], bfr[4];
#pragma unroll
      for (int mt = 0; mt < 4; ++mt) af[mt] = *(const short8*)&As[wm + mt * 16 + l16][ks * 32 + q * 8];
#pragma unroll
      for (int nt = 0; nt < 4; ++nt) bfr[nt] = *(const short8*)&Bs[wn + nt * 16 + l16][ks * 32 + q * 8];
#pragma unroll
      for (int mt = 0; mt < 4; ++mt)
#pragma unroll
        for (int nt = 0; nt < 4; ++nt) acc[mt][nt] = mfma16(af[mt], bfr[nt], acc[mt][nt]);
    }
    __syncthreads();
  }
#pragma unroll
  for (int mt = 0; mt < 4; ++mt)
#pragma unroll
    for (int nt = 0; nt < 4; ++nt)
#pragma unroll
      for (int i = 0; i < 4; ++i) {
        int t = m0 + wm + mt * 16 + q * 4 + i;
        int d = n0 + wn + nt * 16 + l16;
        size_t idx = (size_t)t * D_ + d;
        y[idx] = xin[idx] + alpha * acc[mt][nt][i];
      }
}

// ---------------------------------------------------------------- launch
extern "C" void kernel_launch(void* const* d_in, const int* in_sizes, int n_in,
                              void* d_out, int out_size, void* d_ws, size_t ws_size,
                              hipStream_t stream) {
  const float* x = (const float*)d_in[0];
  const float* Ww = (const float*)d_in[1];
  const float* Wr = (const float*)d_in[2];
  const float* decay = (const float*)d_in[3];
  const float* log_alpha = (const float*)d_in[4];
  float* y = (float*)d_out;

  short* ws = (short*)d_ws;
  const size_t NTD = (size_t)B_ * T_ * D_;   // 33,554,432
  short* rk_bf = ws;                 // rk bf16 (c-major)
  short* vg_bf = rk_bf + NTD;        // vg[b][d][t] = v^T * gw
  short* io_b = vg_bf + NTD;         // inter, then +intra (RMW)
  short* rkT_b = io_b + NTD;         // rkTw[b][e][t] = rk[t-1][e]
  short* Ww_bf = rkT_b + NTD;
  short* Wr_bf = Ww_bf + (size_t)D_ * D_;
  // total ws: 4*NTD + 2*D*D shorts = 272,629,760 bytes (same as passing R2)

  k_cast<<<(int)(NTD / 8 / 256), 256, 0, stream>>>(x, rk_bf, (int)(NTD / 8));
  k_cast<<<512, 256, 0, stream>>>(Ww, Ww_bf, (D_ * D_) / 8);
  k_cast<<<512, 256, 0, stream>>>(Wr, Wr_bf, (D_ * D_) / 8);
  k_transpose<<<dim3(128, 16, 4), 256, 0, stream>>>(rk_bf, rkT_b);
  k_gemm_v<<<dim3(256, 8), 256, 0, stream>>>(Ww_bf, rk_bf, vg_bf, decay);
  k_scan<<<dim3(64, 4), 256, 0, stream>>>(rk_bf, rkT_b, vg_bf, io_b, decay);
  k_intra<<<dim3(128, 4), 256, 0, stream>>>(rk_bf, vg_bf, io_b, decay);
  k_gemm_final<<<dim3(256, 8), 256, 0, stream>>>(io_b, Wr_bf, x, y, log_alpha);
}